// Round 6
// baseline (658.867 us; speedup 1.0000x reference)
//
#include <hip/hip_runtime.h>
#include <cstdint>

#define C_LEN 4096
#define E_DIM 1024
#define NBATCH 4

typedef __attribute__((ext_vector_type(4))) float f32x4;
typedef __attribute__((ext_vector_type(8))) short bf16x8;
typedef __attribute__((ext_vector_type(4))) unsigned short u16x4;

__device__ __forceinline__ unsigned short f2bf(float f) {
  uint32_t u = __builtin_bit_cast(uint32_t, f);
  return (unsigned short)((u + 0x7fffu + ((u >> 16) & 1u)) >> 16);
}

__device__ __forceinline__ void gl_lds16(const void* g, void* l) {
  __builtin_amdgcn_global_load_lds(
      (const __attribute__((address_space(1))) void*)g,
      (__attribute__((address_space(3))) void*)l, 16, 0, 0);
}

// -------- RoPE cos/sin table: [C][E/2] f32 each --------
__global__ __launch_bounds__(256) void rope_table(float* __restrict__ cosT,
                                                  float* __restrict__ sinT) {
  int idx = blockIdx.x * 256 + threadIdx.x;  // over C*E/2
  int pos = idx >> 9;
  int i = idx & 511;
  double inv = exp(((double)(-2 * i) / 1024.0) * 9.210340371976184);
  double a = (double)pos * inv;
  double r = a - 6.283185307179586 * rint(a * 0.15915494309189535);
  float rf = (float)r;
  float s, c;
  __sincosf(rf, &s, &c);
  cosT[idx] = c;
  sinT[idx] = s;
}

// -------- fused f32 -> bf16 convert for x, Wq, Wk, Wv --------
__global__ __launch_bounds__(256) void cvt_all(const float* __restrict__ x,
                                               const float* __restrict__ wq,
                                               const float* __restrict__ wk,
                                               const float* __restrict__ wv,
                                               unsigned short* __restrict__ x_bf,
                                               unsigned short* __restrict__ w_bf) {
  int b = blockIdx.x;
  const float* in;
  unsigned short* out;
  long off;
  if (b < 16384) { in = x; out = x_bf; off = (long)b * 1024; }
  else if (b < 17408) { in = wq; out = w_bf; off = (long)(b - 16384) * 1024; }
  else if (b < 18432) { in = wk; out = w_bf + (1l << 20); off = (long)(b - 17408) * 1024; }
  else { in = wv; out = w_bf + (2l << 20); off = (long)(b - 18432) * 1024; }
  long i = off + threadIdx.x * 4;
  f32x4 v = *(const f32x4*)(in + i);
  u16x4 o = {f2bf(v.x), f2bf(v.y), f2bf(v.z), f2bf(v.w)};
  *(u16x4*)(out + i) = o;
}

// ======== 256x128 BT GEMM, BK=32, 512 threads = 8 waves (4M x 2N), OCC 2 ========
// Double-buffered LDS (48 KiB) -> 2 blocks/CU (__launch_bounds__(512,4) = 128 regs).
// 2 interleaved phases/K-tile {ds_read || stage-next -> bar -> lgkm0 -> 8 MFMA},
// per-tile vmcnt(0) issued 2 phases after the stage; co-resident block hides rest.
// Bank swizzle for 64B rows: granule ^= (row>>1)&3 (2-way/16-lane phase = free);
// inverse-swizzled global source, linear gl_lds dest.
// MODE 0: fused QKV projection (N=3072=[Q|K|V]); RoPE on Q/K, transpose-store V.
// MODE 2: *1/32 + mask, f32 scores. MODE 3: plain f32 out (PV).
template <int MODE>
__global__ __launch_bounds__(512, 4) void gemmA(
    const unsigned short* __restrict__ A, const unsigned short* __restrict__ Bm,
    long sAb, long sBb, long sOb, int nr, int nc, int K, int N,
    unsigned short* __restrict__ oQ, unsigned short* __restrict__ oK,
    unsigned short* __restrict__ oVt, float* __restrict__ oF,
    const float* __restrict__ cosT, const float* __restrict__ sinT,
    const float* __restrict__ mask) {
  __shared__ unsigned short sA[2][256 * 32];  // 2 x 16 KiB
  __shared__ unsigned short sB[2][128 * 32];  // 2 x 8 KiB   (48 KiB total)
  const int tid = threadIdx.x;
  const int lane = tid & 63;
  const int wid = tid >> 6;
  const int wm = wid >> 1, wn = wid & 1;  // 4M x 2N
  const int kgrp = lane >> 4, r16 = lane & 15;

  // XCD chunk (nwg%8==0) + 4x4 supertile decode (nr%4==nc%4==0)
  const int nwg = gridDim.x;
  const int lid = blockIdx.x;
  const int s = (lid & 7) * (nwg >> 3) + (lid >> 3);
  const int scc = nc >> 2;
  const int per_b_st = (nr >> 2) * scc;
  const int sid = s >> 4, inner = s & 15;
  const int bz = sid / per_b_st;
  const int r2 = sid - bz * per_b_st;
  const int srt = r2 / scc, sct = r2 - srt * scc;
  const int rt = srt * 4 + (inner >> 2), ct = sct * 4 + (inner & 3);

  const unsigned short* Ag = A + sAb * bz + (long)rt * 256 * K;
  const unsigned short* Bg = Bm + sBb * bz + (long)ct * 128 * K;

  // Staging: granule G (16B) -> LDS linear at G*8 elems; global col inverse-swizzled.
  auto stA = [&](int p, int half, int j) {
    int G = half * 512 + tid;
    int row = G >> 2, g = G & 3;
    int gc = ((g ^ ((row >> 1) & 3)) << 3);
    gl_lds16(Ag + (long)row * K + j * 32 + gc, &sA[p][G * 8]);
  };
  auto stB = [&](int p, int j) {
    int G = tid;
    int row = G >> 2, g = G & 3;
    int gc = ((g ^ ((row >> 1) & 3)) << 3);
    gl_lds16(Bg + (long)row * K + j * 32 + gc, &sB[p][G * 8]);
  };

  f32x4 acc[4][4];
#pragma unroll
  for (int m = 0; m < 4; ++m)
#pragma unroll
    for (int n = 0; n < 4; ++n) acc[m][n] = {0.f, 0.f, 0.f, 0.f};

  const int NT = K >> 5;
  stA(0, 0, 0); stA(0, 1, 0); stB(0, 0);
  asm volatile("s_waitcnt vmcnt(0)" ::: "memory");
  __builtin_amdgcn_s_barrier();

  for (int j = 0; j < NT; ++j) {
    const int p = j & 1;
    bf16x8 aF[4], bF[4];
    // ---- phase 0: read A(all 4) + B(n0,n1); stage next A-half0 + B ----
#pragma unroll
    for (int m = 0; m < 4; ++m) {
      int row = wm * 64 + m * 16 + r16;
      aF[m] = *(const bf16x8*)&sA[p][row * 32 + ((kgrp ^ ((row >> 1) & 3)) << 3)];
    }
#pragma unroll
    for (int n = 0; n < 2; ++n) {
      int row = wn * 64 + n * 16 + r16;
      bF[n] = *(const bf16x8*)&sB[p][row * 32 + ((kgrp ^ ((row >> 1) & 3)) << 3)];
    }
    if (j + 1 < NT) { stA(p ^ 1, 0, j + 1); stB(p ^ 1, j + 1); }
    __builtin_amdgcn_s_barrier();
    asm volatile("s_waitcnt lgkmcnt(0)" ::: "memory");
    __builtin_amdgcn_sched_barrier(0);
    __builtin_amdgcn_s_setprio(1);
#pragma unroll
    for (int m = 0; m < 4; ++m)
#pragma unroll
      for (int n = 0; n < 2; ++n)
        acc[m][n] = __builtin_amdgcn_mfma_f32_16x16x32_bf16(aF[m], bF[n], acc[m][n], 0, 0, 0);
    __builtin_amdgcn_s_setprio(0);
    __builtin_amdgcn_s_barrier();
    // ---- phase 1: read B(n2,n3); stage next A-half1 ----
#pragma unroll
    for (int n = 2; n < 4; ++n) {
      int row = wn * 64 + n * 16 + r16;
      bF[n] = *(const bf16x8*)&sB[p][row * 32 + ((kgrp ^ ((row >> 1) & 3)) << 3)];
    }
    if (j + 1 < NT) stA(p ^ 1, 1, j + 1);
    __builtin_amdgcn_s_barrier();
    asm volatile("s_waitcnt lgkmcnt(0)" ::: "memory");
    __builtin_amdgcn_sched_barrier(0);
    __builtin_amdgcn_s_setprio(1);
#pragma unroll
    for (int m = 0; m < 4; ++m)
#pragma unroll
      for (int n = 2; n < 4; ++n)
        acc[m][n] = __builtin_amdgcn_mfma_f32_16x16x32_bf16(aF[m], bF[n], acc[m][n], 0, 0, 0);
    __builtin_amdgcn_s_setprio(0);
    __builtin_amdgcn_s_barrier();
    // ---- tile end: next tile's loads (issued 2 phases ago) must have landed ----
    if (j + 1 < NT) asm volatile("s_waitcnt vmcnt(0)" ::: "memory");
    __builtin_amdgcn_s_barrier();
  }

  const int row0 = rt * 256 + wm * 64;
  const int col0 = ct * 128 + wn * 64;
#pragma unroll
  for (int m = 0; m < 4; ++m) {
#pragma unroll
    for (int n = 0; n < 4; ++n) {
#pragma unroll
      for (int r = 0; r < 4; ++r) {
        float v = acc[m][n][r];
        int row = row0 + m * 16 + kgrp * 4 + r;  // C/D: col=lane&15, row=(lane>>4)*4+r
        int col = col0 + n * 16 + r16;
        if (MODE == 0) {
          float pp = __shfl_xor(v, 1);  // RoPE pair partner (col^1, same row/reg)
          int sel = col >> 10;          // 0=Q 1=K 2=V (uniform per 64-col wave slice)
          int lcol = col & 1023;
          if (sel < 2) {
            int pos = row & (C_LEN - 1);
            int i2 = lcol >> 1;
            float c = cosT[pos * (E_DIM / 2) + i2];
            float sn = sinT[pos * (E_DIM / 2) + i2];
            float rv = v * c + ((lcol & 1) ? pp * sn : -pp * sn);
            unsigned short* o = sel ? oK : oQ;
            o[(long)row * E_DIM + lcol] = f2bf(rv);
          } else {
            int b = row >> 12;
            int cc = row & (C_LEN - 1);
            oVt[(long)b * E_DIM * C_LEN + (long)lcol * C_LEN + cc] = f2bf(v);
          }
        } else if (MODE == 2) {
          float sc = v * 0.03125f + mask[(long)row * C_LEN + col];
          oF[sOb * bz + (long)row * C_LEN + col] = sc;
        } else {
          oF[sOb * bz + (long)row * N + col] = v;
        }
      }
    }
  }
}

// -------- row softmax: normalize f32 weights in place + emit bf16 copy --------
// NT-load raw scores (one-shot read), NT-store final f32 weights (full-line).
__global__ __launch_bounds__(256) void softmax_rows(float* __restrict__ w,
                                                    unsigned short* __restrict__ pb) {
  long row = blockIdx.x;
  float* p = w + row * C_LEN;
  unsigned short* pbp = pb + row * C_LEN;
  int t = threadIdx.x;
  int wid = t >> 6;
  f32x4 v[4];
  float mx = -3.4e38f;
#pragma unroll
  for (int j = 0; j < 4; ++j) {
    v[j] = __builtin_nontemporal_load((const f32x4*)(p + j * 1024 + t * 4));
    mx = fmaxf(mx, fmaxf(fmaxf(v[j].x, v[j].y), fmaxf(v[j].z, v[j].w)));
  }
#pragma unroll
  for (int o = 1; o < 64; o <<= 1) mx = fmaxf(mx, __shfl_xor(mx, o));
  __shared__ float redm[4];
  if ((t & 63) == 0) redm[wid] = mx;
  __syncthreads();
  mx = fmaxf(fmaxf(redm[0], redm[1]), fmaxf(redm[2], redm[3]));
  float sum = 0.f;
#pragma unroll
  for (int j = 0; j < 4; ++j) {
    v[j].x = __expf(v[j].x - mx);
    v[j].y = __expf(v[j].y - mx);
    v[j].z = __expf(v[j].z - mx);
    v[j].w = __expf(v[j].w - mx);
    sum += v[j].x + v[j].y + v[j].z + v[j].w;
  }
#pragma unroll
  for (int o = 1; o < 64; o <<= 1) sum += __shfl_xor(sum, o);
  __shared__ float reds[4];
  if ((t & 63) == 0) reds[wid] = sum;
  __syncthreads();
  sum = reds[0] + reds[1] + reds[2] + reds[3];
  float inv = 1.0f / sum;
#pragma unroll
  for (int j = 0; j < 4; ++j) {
    v[j].x *= inv;
    v[j].y *= inv;
    v[j].z *= inv;
    v[j].w *= inv;
    __builtin_nontemporal_store(v[j], (f32x4*)(p + j * 1024 + t * 4));
    u16x4 o16 = {f2bf(v[j].x), f2bf(v[j].y), f2bf(v[j].z), f2bf(v[j].w)};
    *(u16x4*)(pbp + j * 1024 + t * 4) = o16;
  }
}

extern "C" void kernel_launch(void* const* d_in, const int* in_sizes, int n_in,
                              void* d_out, int out_size, void* d_ws, size_t ws_size,
                              hipStream_t stream) {
  const float* x = (const float*)d_in[0];
  const float* mask = (const float*)d_in[1];
  const float* Wq = (const float*)d_in[2];
  const float* Wk = (const float*)d_in[3];
  const float* Wv = (const float*)d_in[4];
  float* out = (float*)d_out;                           // [B][C][E]
  float* weights = out + (long)NBATCH * C_LEN * E_DIM;  // [B][C][C]

  char* ws = (char*)d_ws;
  const bool big = ws_size >= (160ull << 20);
  float* cosT = (float*)(ws);
  float* sinT = (float*)(ws + (8l << 20));
  unsigned short* x_bf = (unsigned short*)(ws + (16l << 20));
  unsigned short* W_bf = (unsigned short*)(ws + (48l << 20));  // [3072][1024] = Q|K|V
  unsigned short* Q_bf = (unsigned short*)(ws + (54l << 20));
  unsigned short* K_bf = (unsigned short*)(ws + (86l << 20));
  unsigned short* Vt = (unsigned short*)(ws + (big ? (128l << 20) : (118l << 20)));
  unsigned short* P_bf = (unsigned short*)(ws);

  dim3 blk(256);
  dim3 blk512(512);

  rope_table<<<dim3((C_LEN * (E_DIM / 2)) / 256), blk, 0, stream>>>(cosT, sinT);
  cvt_all<<<dim3(19456), blk, 0, stream>>>(x, Wq, Wk, Wv, x_bf, W_bf);

  // fused QKV projection: 64 rt x 24 ct = 1536 blocks
  gemmA<0><<<dim3(1536), blk512, 0, stream>>>(
      x_bf, W_bf, 0, 0, 0, 64, 24, E_DIM, 3 * E_DIM,
      Q_bf, K_bf, Vt, nullptr, cosT, sinT, nullptr);

  // scores = QK^T/32 + mask -> 16 rt x 32 ct x 4 bz = 2048 blocks
  gemmA<2><<<dim3(2048), blk512, 0, stream>>>(
      Q_bf, K_bf, (long)C_LEN * E_DIM, (long)C_LEN * E_DIM, (long)C_LEN * C_LEN,
      16, 32, E_DIM, C_LEN, nullptr, nullptr, nullptr, weights, nullptr, nullptr, mask);

  if (big) {
    softmax_rows<<<dim3(NBATCH * C_LEN), blk, 0, stream>>>(weights, P_bf);
    // out = P @ V: 16 rt x 8 ct x 4 bz = 512 blocks (2/CU)
    gemmA<3><<<dim3(512), blk512, 0, stream>>>(
        P_bf, Vt, (long)C_LEN * C_LEN, (long)E_DIM * C_LEN, (long)C_LEN * E_DIM,
        16, 8, C_LEN, E_DIM, nullptr, nullptr, nullptr, out, nullptr, nullptr, nullptr);
  } else {
    for (int h = 0; h < 2; ++h) {
      float* wgt = weights + (long)h * 2 * C_LEN * C_LEN;
      softmax_rows<<<dim3(2 * C_LEN), blk, 0, stream>>>(wgt, P_bf);
      gemmA<3><<<dim3(256), blk512, 0, stream>>>(
          P_bf, Vt + (long)h * 2 * E_DIM * C_LEN, (long)C_LEN * C_LEN, (long)E_DIM * C_LEN,
          (long)C_LEN * E_DIM, 16, 8, C_LEN, E_DIM,
          nullptr, nullptr, nullptr, out + (long)h * 2 * C_LEN * E_DIM,
          nullptr, nullptr, nullptr);
    }
  }
}

// Round 7
// 644.429 us; speedup vs baseline: 1.0224x; 1.0224x over previous
//
#include <hip/hip_runtime.h>
#include <cstdint>

#define C_LEN 4096
#define E_DIM 1024
#define NBATCH 4

typedef __attribute__((ext_vector_type(4))) float f32x4;
typedef __attribute__((ext_vector_type(8))) short bf16x8;
typedef __attribute__((ext_vector_type(4))) unsigned short u16x4;

__device__ __forceinline__ unsigned short f2bf(float f) {
  uint32_t u = __builtin_bit_cast(uint32_t, f);
  return (unsigned short)((u + 0x7fffu + ((u >> 16) & 1u)) >> 16);
}

__device__ __forceinline__ void gl_lds16(const void* g, void* l) {
  __builtin_amdgcn_global_load_lds(
      (const __attribute__((address_space(1))) void*)g,
      (__attribute__((address_space(3))) void*)l, 16, 0, 0);
}

// -------- RoPE cos/sin table: [C][E/2] f32 each --------
__global__ __launch_bounds__(256) void rope_table(float* __restrict__ cosT,
                                                  float* __restrict__ sinT) {
  int idx = blockIdx.x * 256 + threadIdx.x;  // over C*E/2
  int pos = idx >> 9;
  int i = idx & 511;
  double inv = exp(((double)(-2 * i) / 1024.0) * 9.210340371976184);
  double a = (double)pos * inv;
  double r = a - 6.283185307179586 * rint(a * 0.15915494309189535);
  float rf = (float)r;
  float s, c;
  __sincosf(rf, &s, &c);
  cosT[idx] = c;
  sinT[idx] = s;
}

// -------- fused f32 -> bf16 convert for x, Wq, Wk, Wv --------
__global__ __launch_bounds__(256) void cvt_all(const float* __restrict__ x,
                                               const float* __restrict__ wq,
                                               const float* __restrict__ wk,
                                               const float* __restrict__ wv,
                                               unsigned short* __restrict__ x_bf,
                                               unsigned short* __restrict__ w_bf) {
  int b = blockIdx.x;
  const float* in;
  unsigned short* out;
  long off;
  if (b < 16384) { in = x; out = x_bf; off = (long)b * 1024; }
  else if (b < 17408) { in = wq; out = w_bf; off = (long)(b - 16384) * 1024; }
  else if (b < 18432) { in = wk; out = w_bf + (1l << 20); off = (long)(b - 17408) * 1024; }
  else { in = wv; out = w_bf + (2l << 20); off = (long)(b - 18432) * 1024; }
  long i = off + threadIdx.x * 4;
  f32x4 v = *(const f32x4*)(in + i);
  u16x4 o = {f2bf(v.x), f2bf(v.y), f2bf(v.z), f2bf(v.w)};
  *(u16x4*)(out + i) = o;
}

// ======== 256x128 BT GEMM, BK=32, 512 threads = 8 waves (4M x 2N), OCC 2 ========
// TRIPLE-buffered LDS (72 KiB) -> one barrier + one counted vmcnt(3) per K-tile.
// Tile j computes from buf j%3 while staging tile j+2 into buf (j+2)%3 (sealed
// one barrier ago). All of a wave's ds_reads are lgkm-consumed by its MFMAs
// before the tile-end barrier, so no intra-tile barriers are needed.
// Bank swizzle for 64B rows: granule ^= (row>>1)&3; inverse-swizzled global
// source + linear gl_lds dest (both-sides rule). Supertile + XCD chunk decode.
// MODE 0: fused QKV projection (N=3072=[Q|K|V]); RoPE on Q/K, transpose-store V.
// MODE 2: *1/32 + mask, f32 scores. MODE 3: plain f32 out (PV).
template <int MODE>
__global__ __launch_bounds__(512, 4) void gemmA(
    const unsigned short* __restrict__ A, const unsigned short* __restrict__ Bm,
    long sAb, long sBb, long sOb, int nr, int nc, int K, int N,
    unsigned short* __restrict__ oQ, unsigned short* __restrict__ oK,
    unsigned short* __restrict__ oVt, float* __restrict__ oF,
    const float* __restrict__ cosT, const float* __restrict__ sinT,
    const float* __restrict__ mask) {
  __shared__ unsigned short sA[3][256 * 32];  // 3 x 16 KiB
  __shared__ unsigned short sB[3][128 * 32];  // 3 x 8 KiB   (72 KiB total)
  const int tid = threadIdx.x;
  const int lane = tid & 63;
  const int wid = tid >> 6;
  const int wm = wid >> 1, wn = wid & 1;  // 4M x 2N
  const int kgrp = lane >> 4, r16 = lane & 15;

  // XCD chunk (nwg%8==0) + 4x4 supertile decode (nr%4==nc%4==0)
  const int nwg = gridDim.x;
  const int lid = blockIdx.x;
  const int s = (lid & 7) * (nwg >> 3) + (lid >> 3);
  const int scc = nc >> 2;
  const int per_b_st = (nr >> 2) * scc;
  const int sid = s >> 4, inner = s & 15;
  const int bz = sid / per_b_st;
  const int r2 = sid - bz * per_b_st;
  const int srt = r2 / scc, sct = r2 - srt * scc;
  const int rt = srt * 4 + (inner >> 2), ct = sct * 4 + (inner & 3);

  const unsigned short* Ag = A + sAb * bz + (long)rt * 256 * K;
  const unsigned short* Bg = Bm + sBb * bz + (long)ct * 128 * K;

  // Staging addresses (invariant): granule G -> LDS linear G*8 elems; global
  // column inverse-swizzled by the read involution.
  const int g_row0 = tid >> 2, g_g0 = tid & 3;
  const int g_c0 = ((g_g0 ^ ((g_row0 >> 1) & 3)) << 3);
  const int g_row1 = (512 + tid) >> 2, g_g1 = tid & 3;
  const int g_c1 = ((g_g1 ^ ((g_row1 >> 1) & 3)) << 3);

  auto stage = [&](int t, int b) {
    const unsigned short* a = Ag + t * 32;
    gl_lds16(a + (long)g_row0 * K + g_c0, &sA[b][tid * 8]);
    gl_lds16(a + (long)g_row1 * K + g_c1, &sA[b][(512 + tid) * 8]);
    gl_lds16(Bg + (long)g_row0 * K + t * 32 + g_c0, &sB[b][tid * 8]);
  };

  f32x4 acc[4][4];
#pragma unroll
  for (int m = 0; m < 4; ++m)
#pragma unroll
    for (int n = 0; n < 4; ++n) acc[m][n] = {0.f, 0.f, 0.f, 0.f};

  const int NT = K >> 5;
  stage(0, 0);
  stage(1, 1);
  asm volatile("s_waitcnt vmcnt(3)" ::: "memory");  // tile 0 landed; tile 1 in flight
  __builtin_amdgcn_s_barrier();
  __builtin_amdgcn_sched_barrier(0);

  int bj = 0;
  for (int j = 0; j < NT; ++j) {
    bf16x8 aF[4], bF[4];
#pragma unroll
    for (int m = 0; m < 4; ++m) {
      int row = wm * 64 + m * 16 + r16;
      aF[m] = *(const bf16x8*)&sA[bj][row * 32 + ((kgrp ^ ((row >> 1) & 3)) << 3)];
    }
#pragma unroll
    for (int n = 0; n < 4; ++n) {
      int row = wn * 64 + n * 16 + r16;
      bF[n] = *(const bf16x8*)&sB[bj][row * 32 + ((kgrp ^ ((row >> 1) & 3)) << 3)];
    }
    int bn = bj + 2;
    if (bn >= 3) bn -= 3;
    if (j + 2 < NT) stage(j + 2, bn);  // into buffer sealed one barrier ago
    __builtin_amdgcn_s_setprio(1);
#pragma unroll
    for (int m = 0; m < 4; ++m)
#pragma unroll
      for (int n = 0; n < 4; ++n)
        acc[m][n] = __builtin_amdgcn_mfma_f32_16x16x32_bf16(aF[m], bF[n], acc[m][n], 0, 0, 0);
    __builtin_amdgcn_s_setprio(0);
    if (j + 1 < NT) {
      // counted: tile j+1's 3 loads retired, tile j+2's 3 may remain in flight
      if (j + 2 < NT) {
        asm volatile("s_waitcnt vmcnt(3)" ::: "memory");
      } else {
        asm volatile("s_waitcnt vmcnt(0)" ::: "memory");
      }
      __builtin_amdgcn_s_barrier();
      __builtin_amdgcn_sched_barrier(0);  // keep next tile's ds_reads below barrier
    }
    if (++bj == 3) bj = 0;
  }

  const int row0 = rt * 256 + wm * 64;
  const int col0 = ct * 128 + wn * 64;
#pragma unroll
  for (int m = 0; m < 4; ++m) {
#pragma unroll
    for (int n = 0; n < 4; ++n) {
#pragma unroll
      for (int r = 0; r < 4; ++r) {
        float v = acc[m][n][r];
        int row = row0 + m * 16 + kgrp * 4 + r;  // C/D: col=lane&15, row=(lane>>4)*4+r
        int col = col0 + n * 16 + r16;
        if (MODE == 0) {
          float pp = __shfl_xor(v, 1);  // RoPE pair partner (col^1, same row/reg)
          int sel = col >> 10;          // 0=Q 1=K 2=V (uniform per 64-col wave slice)
          int lcol = col & 1023;
          if (sel < 2) {
            int pos = row & (C_LEN - 1);
            int i2 = lcol >> 1;
            float c = cosT[pos * (E_DIM / 2) + i2];
            float sn = sinT[pos * (E_DIM / 2) + i2];
            float rv = v * c + ((lcol & 1) ? pp * sn : -pp * sn);
            unsigned short* o = sel ? oK : oQ;
            o[(long)row * E_DIM + lcol] = f2bf(rv);
          } else {
            int b = row >> 12;
            int cc = row & (C_LEN - 1);
            oVt[(long)b * E_DIM * C_LEN + (long)lcol * C_LEN + cc] = f2bf(v);
          }
        } else if (MODE == 2) {
          float sc = v * 0.03125f + mask[(long)row * C_LEN + col];
          oF[sOb * bz + (long)row * C_LEN + col] = sc;
        } else {
          oF[sOb * bz + (long)row * N + col] = v;
        }
      }
    }
  }
}

// -------- row softmax: normalize f32 weights in place + emit bf16 copy --------
__global__ __launch_bounds__(256) void softmax_rows(float* __restrict__ w,
                                                    unsigned short* __restrict__ pb) {
  long row = blockIdx.x;
  float* p = w + row * C_LEN;
  unsigned short* pbp = pb + row * C_LEN;
  int t = threadIdx.x;
  int wid = t >> 6;
  f32x4 v[4];
  float mx = -3.4e38f;
#pragma unroll
  for (int j = 0; j < 4; ++j) {
    v[j] = __builtin_nontemporal_load((const f32x4*)(p + j * 1024 + t * 4));
    mx = fmaxf(mx, fmaxf(fmaxf(v[j].x, v[j].y), fmaxf(v[j].z, v[j].w)));
  }
#pragma unroll
  for (int o = 1; o < 64; o <<= 1) mx = fmaxf(mx, __shfl_xor(mx, o));
  __shared__ float redm[4];
  if ((t & 63) == 0) redm[wid] = mx;
  __syncthreads();
  mx = fmaxf(fmaxf(redm[0], redm[1]), fmaxf(redm[2], redm[3]));
  float sum = 0.f;
#pragma unroll
  for (int j = 0; j < 4; ++j) {
    v[j].x = __expf(v[j].x - mx);
    v[j].y = __expf(v[j].y - mx);
    v[j].z = __expf(v[j].z - mx);
    v[j].w = __expf(v[j].w - mx);
    sum += v[j].x + v[j].y + v[j].z + v[j].w;
  }
#pragma unroll
  for (int o = 1; o < 64; o <<= 1) sum += __shfl_xor(sum, o);
  __shared__ float reds[4];
  if ((t & 63) == 0) reds[wid] = sum;
  __syncthreads();
  sum = reds[0] + reds[1] + reds[2] + reds[3];
  float inv = 1.0f / sum;
#pragma unroll
  for (int j = 0; j < 4; ++j) {
    v[j].x *= inv;
    v[j].y *= inv;
    v[j].z *= inv;
    v[j].w *= inv;
    __builtin_nontemporal_store(v[j], (f32x4*)(p + j * 1024 + t * 4));
    u16x4 o16 = {f2bf(v[j].x), f2bf(v[j].y), f2bf(v[j].z), f2bf(v[j].w)};
    *(u16x4*)(pbp + j * 1024 + t * 4) = o16;
  }
}

extern "C" void kernel_launch(void* const* d_in, const int* in_sizes, int n_in,
                              void* d_out, int out_size, void* d_ws, size_t ws_size,
                              hipStream_t stream) {
  const float* x = (const float*)d_in[0];
  const float* mask = (const float*)d_in[1];
  const float* Wq = (const float*)d_in[2];
  const float* Wk = (const float*)d_in[3];
  const float* Wv = (const float*)d_in[4];
  float* out = (float*)d_out;                           // [B][C][E]
  float* weights = out + (long)NBATCH * C_LEN * E_DIM;  // [B][C][C]

  char* ws = (char*)d_ws;
  const bool big = ws_size >= (160ull << 20);
  float* cosT = (float*)(ws);
  float* sinT = (float*)(ws + (8l << 20));
  unsigned short* x_bf = (unsigned short*)(ws + (16l << 20));
  unsigned short* W_bf = (unsigned short*)(ws + (48l << 20));  // [3072][1024] = Q|K|V
  unsigned short* Q_bf = (unsigned short*)(ws + (54l << 20));
  unsigned short* K_bf = (unsigned short*)(ws + (86l << 20));
  unsigned short* Vt = (unsigned short*)(ws + (big ? (128l << 20) : (118l << 20)));
  unsigned short* P_bf = (unsigned short*)(ws);

  dim3 blk(256);
  dim3 blk512(512);

  rope_table<<<dim3((C_LEN * (E_DIM / 2)) / 256), blk, 0, stream>>>(cosT, sinT);
  cvt_all<<<dim3(19456), blk, 0, stream>>>(x, Wq, Wk, Wv, x_bf, W_bf);

  // fused QKV projection: 64 rt x 24 ct = 1536 blocks
  gemmA<0><<<dim3(1536), blk512, 0, stream>>>(
      x_bf, W_bf, 0, 0, 0, 64, 24, E_DIM, 3 * E_DIM,
      Q_bf, K_bf, Vt, nullptr, cosT, sinT, nullptr);

  // scores = QK^T/32 + mask -> 16 rt x 32 ct x 4 bz = 2048 blocks
  gemmA<2><<<dim3(2048), blk512, 0, stream>>>(
      Q_bf, K_bf, (long)C_LEN * E_DIM, (long)C_LEN * E_DIM, (long)C_LEN * C_LEN,
      16, 32, E_DIM, C_LEN, nullptr, nullptr, nullptr, weights, nullptr, nullptr, mask);

  if (big) {
    softmax_rows<<<dim3(NBATCH * C_LEN), blk, 0, stream>>>(weights, P_bf);
    // out = P @ V: 16 rt x 8 ct x 4 bz = 512 blocks (2/CU)
    gemmA<3><<<dim3(512), blk512, 0, stream>>>(
        P_bf, Vt, (long)C_LEN * C_LEN, (long)E_DIM * C_LEN, (long)C_LEN * E_DIM,
        16, 8, C_LEN, E_DIM, nullptr, nullptr, nullptr, out, nullptr, nullptr, nullptr);
  } else {
    for (int h = 0; h < 2; ++h) {
      float* wgt = weights + (long)h * 2 * C_LEN * C_LEN;
      softmax_rows<<<dim3(2 * C_LEN), blk, 0, stream>>>(wgt, P_bf);
      gemmA<3><<<dim3(256), blk512, 0, stream>>>(
          P_bf, Vt + (long)h * 2 * E_DIM * C_LEN, (long)C_LEN * C_LEN, (long)E_DIM * C_LEN,
          (long)C_LEN * E_DIM, 16, 8, C_LEN, E_DIM,
          nullptr, nullptr, nullptr, out + (long)h * 2 * C_LEN * E_DIM,
          nullptr, nullptr, nullptr);
    }
  }
}

// Round 8
// 624.864 us; speedup vs baseline: 1.0544x; 1.0313x over previous
//
#include <hip/hip_runtime.h>
#include <cstdint>

#define C_LEN 4096
#define E_DIM 1024
#define NBATCH 4

typedef __attribute__((ext_vector_type(4))) float f32x4;
typedef __attribute__((ext_vector_type(8))) short bf16x8;
typedef __attribute__((ext_vector_type(4))) unsigned short u16x4;

__device__ __forceinline__ unsigned short f2bf(float f) {
  uint32_t u = __builtin_bit_cast(uint32_t, f);
  return (unsigned short)((u + 0x7fffu + ((u >> 16) & 1u)) >> 16);
}

__device__ __forceinline__ void gl_lds16(const void* g, void* l) {
  __builtin_amdgcn_global_load_lds(
      (const __attribute__((address_space(1))) void*)g,
      (__attribute__((address_space(3))) void*)l, 16, 0, 0);
}

#define BAR() __builtin_amdgcn_s_barrier()
#define LGKM0() do { asm volatile("s_waitcnt lgkmcnt(0)" ::: "memory"); \
                     __builtin_amdgcn_sched_barrier(0); } while (0)
#define VMC(n) asm volatile("s_waitcnt vmcnt(" #n ")" ::: "memory")

// -------- RoPE cos/sin table: [C][E/2] f32 each --------
__global__ __launch_bounds__(256) void rope_table(float* __restrict__ cosT,
                                                  float* __restrict__ sinT) {
  int idx = blockIdx.x * 256 + threadIdx.x;  // over C*E/2
  int pos = idx >> 9;
  int i = idx & 511;
  double inv = exp(((double)(-2 * i) / 1024.0) * 9.210340371976184);
  double a = (double)pos * inv;
  double r = a - 6.283185307179586 * rint(a * 0.15915494309189535);
  float rf = (float)r;
  float s, c;
  __sincosf(rf, &s, &c);
  cosT[idx] = c;
  sinT[idx] = s;
}

// -------- fused f32 -> bf16 convert for x, Wq, Wk, Wv --------
__global__ __launch_bounds__(256) void cvt_all(const float* __restrict__ x,
                                               const float* __restrict__ wq,
                                               const float* __restrict__ wk,
                                               const float* __restrict__ wv,
                                               unsigned short* __restrict__ x_bf,
                                               unsigned short* __restrict__ w_bf) {
  int b = blockIdx.x;
  const float* in;
  unsigned short* out;
  long off;
  if (b < 16384) { in = x; out = x_bf; off = (long)b * 1024; }
  else if (b < 17408) { in = wq; out = w_bf; off = (long)(b - 16384) * 1024; }
  else if (b < 18432) { in = wk; out = w_bf + (1l << 20); off = (long)(b - 17408) * 1024; }
  else { in = wv; out = w_bf + (2l << 20); off = (long)(b - 18432) * 1024; }
  long i = off + threadIdx.x * 4;
  f32x4 v = *(const f32x4*)(in + i);
  u16x4 o = {f2bf(v.x), f2bf(v.y), f2bf(v.z), f2bf(v.w)};
  *(u16x4*)(out + i) = o;
}

// ======== 256x256 8-phase GEMM (m201 template), BK=64, 2 K-tiles/iter ========
// 512 threads = 8 waves (2M x 4N), wave tile 128x64. LDS 128 KiB:
// [buf(2)][op A/B][half][128][64] bf16. Each phase: {ds-reads || stage 1
// half-tile -> barrier -> lgkm0 -> setprio 16 MFMA -> barrier}. Stage slots
// ph1..8 = {A[t1]h0, A[t1]h1, B[t2]h0, B[t2]h1, A[t2]h0, A[t2]h1, B[t3]h0,
// B[t3]h1} (each after its buffer-half's seal barrier). vmcnt(4) at ph4/ph8
// only: retires all but the 2 youngest half-tiles -> consumed tile landed.
// Swizzle: granule(16B) ^= row&7 within each [128][64] half; inverse-permuted
// global source + linear gl_lds dest.
// MODE 0: fused QKV projection (N=3072=[Q|K|V]); RoPE on Q/K, transpose V.
// MODE 2: *1/32 + mask, f32 scores. MODE 3: plain f32 out (PV).
template <int MODE>
__global__ __launch_bounds__(512, 1) void gemm8(
    const unsigned short* __restrict__ A, const unsigned short* __restrict__ Bm,
    long sAb, long sBb, long sOb, int nr, int nc, int K, int N,
    unsigned short* __restrict__ oQ, unsigned short* __restrict__ oK,
    unsigned short* __restrict__ oVt, float* __restrict__ oF,
    const float* __restrict__ cosT, const float* __restrict__ sinT,
    const float* __restrict__ mask) {
  __shared__ unsigned short lds[2][2][2][128 * 64];  // 128 KiB
  const int tid = threadIdx.x;
  const int lane = tid & 63;
  const int wid = tid >> 6;
  const int wm = wid >> 2, wn = wid & 3;  // 2M x 4N
  const int kgrp = lane >> 4, r16 = lane & 15;

  // XCD chunk (nwg%8==0) + 4x4 supertile decode (nr%4==0, nc%4==0)
  const int nwg = gridDim.x;
  const int lid = blockIdx.x;
  const int s = (lid & 7) * (nwg >> 3) + (lid >> 3);
  const int scc = nc >> 2;
  const int per_b_st = (nr >> 2) * scc;
  const int sid = s >> 4, inner = s & 15;
  const int bz = sid / per_b_st;
  const int r2 = sid - bz * per_b_st;
  const int srt = r2 / scc, sct = r2 - srt * scc;
  const int rt = srt * 4 + (inner >> 2), ct = sct * 4 + (inner & 3);

  const unsigned short* Ag = A + sAb * bz + (long)rt * 256 * K;
  const unsigned short* Bg = Bm + sBb * bz + (long)ct * 256 * K;

  // stage one half-tile (128x64) = 2 gl_lds/thread; LDS linear, src col
  // granule inverse-swizzled by the read involution (g ^= row&7).
  auto stA = [&](int buf, int half, int t) {
#pragma unroll
    for (int q = 0; q < 2; ++q) {
      int G = q * 512 + tid;
      int r = G >> 3, g = G & 7;
      gl_lds16(Ag + (long)(half * 128 + r) * K + t * 64 + ((g ^ (r & 7)) << 3),
               &lds[buf][0][half][G * 8]);
    }
  };
  auto stB = [&](int buf, int half, int t) {
#pragma unroll
    for (int q = 0; q < 2; ++q) {
      int G = q * 512 + tid;
      int r = G >> 3, g = G & 7;
      gl_lds16(Bg + (long)(half * 128 + r) * K + t * 64 + ((g ^ (r & 7)) << 3),
               &lds[buf][1][half][G * 8]);
    }
  };

  f32x4 acc[8][4];
#pragma unroll
  for (int m = 0; m < 8; ++m)
#pragma unroll
    for (int n = 0; n < 4; ++n) acc[m][n] = {0.f, 0.f, 0.f, 0.f};

  bf16x8 aF[8], bF0[4], bF1[4];
  auto rdA = [&](int buf, int mh) {
#pragma unroll
    for (int m = 0; m < 4; ++m) {
      int row = mh * 64 + m * 16 + r16;
#pragma unroll
      for (int ks = 0; ks < 2; ++ks)
        aF[m * 2 + ks] = *(const bf16x8*)&lds[buf][0][wm]
            [row * 64 + ((((ks << 2) + kgrp) ^ (row & 7)) << 3)];
    }
  };
  auto rdB = [&](int buf, int nh, bf16x8* d) {
#pragma unroll
    for (int n = 0; n < 2; ++n) {
      int row = (wn & 1) * 64 + nh * 32 + n * 16 + r16;
#pragma unroll
      for (int ks = 0; ks < 2; ++ks)
        d[n * 2 + ks] = *(const bf16x8*)&lds[buf][1][wn >> 1]
            [row * 64 + ((((ks << 2) + kgrp) ^ (row & 7)) << 3)];
    }
  };
  auto mm = [&](bf16x8* bf, int mh, int nh) {
    __builtin_amdgcn_s_setprio(1);
#pragma unroll
    for (int ks = 0; ks < 2; ++ks)
#pragma unroll
      for (int m = 0; m < 4; ++m)
#pragma unroll
        for (int n = 0; n < 2; ++n)
          acc[mh * 4 + m][nh * 2 + n] = __builtin_amdgcn_mfma_f32_16x16x32_bf16(
              aF[m * 2 + ks], bf[n * 2 + ks], acc[mh * 4 + m][nh * 2 + n], 0, 0, 0);
    __builtin_amdgcn_s_setprio(0);
  };

  const int NIT = K >> 7;  // 2 K-tiles (BK=64) per iteration
  // Prologue: tiles 0 (buf0) and 1 (buf1) fully staged; retire tile 0's 8 loads.
  stA(0, 0, 0); stA(0, 1, 0); stB(0, 0, 0); stB(0, 1, 0);
  stA(1, 0, 1); stA(1, 1, 1); stB(1, 0, 1); stB(1, 1, 1);
  VMC(8);
  BAR();
  __builtin_amdgcn_sched_barrier(0);

  for (int it = 0; it < NIT; ++it) {
    const int t1 = 2 * it + 1, t2 = 2 * it + 2, t3 = 2 * it + 3;
    const bool more = (it + 1 < NIT);
    // ---- ph1: t0 (mh0,nh0) ---- buf1-A sealed at prev ph7
    rdA(0, 0); rdB(0, 0, bF0);
    if (it > 0) stA(1, 0, t1);
    BAR(); LGKM0();
    mm(bF0, 0, 0);
    BAR();
    // ---- ph2: t0 (mh0,nh1) ----
    rdB(0, 1, bF1);
    if (it > 0) stA(1, 1, t1);
    BAR(); LGKM0();
    mm(bF1, 0, 1);
    BAR();
    // ---- ph3: t0 (mh1,nh1) ---- buf0-B sealed at ph2 end
    rdA(0, 1);
    if (more) stB(0, 0, t2);
    BAR(); LGKM0();
    mm(bF1, 1, 1);
    BAR();
    // ---- ph4: t0 (mh1,nh0) ---- vmcnt: tile t1 fully landed for ph5
    if (more) stB(0, 1, t2);
    BAR();
    mm(bF0, 1, 0);
    if (more) { VMC(4); } else { VMC(0); }
    BAR();
    // ---- ph5: t1 (mh0,nh0) ---- buf0-A sealed at ph3 end
    rdA(1, 0); rdB(1, 0, bF0);
    if (more) stA(0, 0, t2);
    BAR(); LGKM0();
    mm(bF0, 0, 0);
    BAR();
    // ---- ph6: t1 (mh0,nh1) ----
    rdB(1, 1, bF1);
    if (more) stA(0, 1, t2);
    BAR(); LGKM0();
    mm(bF1, 0, 1);
    BAR();
    // ---- ph7: t1 (mh1,nh1) ---- buf1-B sealed at ph6 end
    rdA(1, 1);
    if (more) stB(1, 0, t3);
    BAR(); LGKM0();
    mm(bF1, 1, 1);
    BAR();
    // ---- ph8: t1 (mh1,nh0) ---- vmcnt: tile t2 fully landed for next ph1
    if (more) stB(1, 1, t3);
    BAR();
    mm(bF0, 1, 0);
    if (more) { VMC(4); BAR(); }
  }

  const int row0 = rt * 256 + wm * 128;
  const int col0 = ct * 256 + wn * 64;
#pragma unroll
  for (int m = 0; m < 8; ++m) {
#pragma unroll
    for (int n = 0; n < 4; ++n) {
#pragma unroll
      for (int r = 0; r < 4; ++r) {
        float v = acc[m][n][r];
        int row = row0 + m * 16 + kgrp * 4 + r;  // C/D: col=lane&15, row=(lane>>4)*4+r
        int col = col0 + n * 16 + r16;
        if (MODE == 0) {
          float pp = __shfl_xor(v, 1);  // RoPE pair partner (col^1, same row/reg)
          int sel = col >> 10;          // 0=Q 1=K 2=V (uniform per 64-col wave slice)
          int lcol = col & 1023;
          if (sel < 2) {
            int pos = row & (C_LEN - 1);
            int i2 = lcol >> 1;
            float c = cosT[pos * (E_DIM / 2) + i2];
            float sn = sinT[pos * (E_DIM / 2) + i2];
            float rv = v * c + ((lcol & 1) ? pp * sn : -pp * sn);
            unsigned short* o = sel ? oK : oQ;
            o[(long)row * E_DIM + lcol] = f2bf(rv);
          } else {
            int b = row >> 12;
            int cc = row & (C_LEN - 1);
            oVt[(long)b * E_DIM * C_LEN + (long)lcol * C_LEN + cc] = f2bf(v);
          }
        } else if (MODE == 2) {
          float sc = v * 0.03125f + mask[(long)row * C_LEN + col];
          oF[sOb * bz + (long)row * C_LEN + col] = sc;
        } else {
          oF[sOb * bz + (long)row * N + col] = v;
        }
      }
    }
  }
}

// -------- row softmax: normalize f32 weights in place + emit bf16 copy --------
__global__ __launch_bounds__(256) void softmax_rows(float* __restrict__ w,
                                                    unsigned short* __restrict__ pb) {
  long row = blockIdx.x;
  float* p = w + row * C_LEN;
  unsigned short* pbp = pb + row * C_LEN;
  int t = threadIdx.x;
  int wid = t >> 6;
  f32x4 v[4];
  float mx = -3.4e38f;
#pragma unroll
  for (int j = 0; j < 4; ++j) {
    v[j] = __builtin_nontemporal_load((const f32x4*)(p + j * 1024 + t * 4));
    mx = fmaxf(mx, fmaxf(fmaxf(v[j].x, v[j].y), fmaxf(v[j].z, v[j].w)));
  }
#pragma unroll
  for (int o = 1; o < 64; o <<= 1) mx = fmaxf(mx, __shfl_xor(mx, o));
  __shared__ float redm[4];
  if ((t & 63) == 0) redm[wid] = mx;
  __syncthreads();
  mx = fmaxf(fmaxf(redm[0], redm[1]), fmaxf(redm[2], redm[3]));
  float sum = 0.f;
#pragma unroll
  for (int j = 0; j < 4; ++j) {
    v[j].x = __expf(v[j].x - mx);
    v[j].y = __expf(v[j].y - mx);
    v[j].z = __expf(v[j].z - mx);
    v[j].w = __expf(v[j].w - mx);
    sum += v[j].x + v[j].y + v[j].z + v[j].w;
  }
#pragma unroll
  for (int o = 1; o < 64; o <<= 1) sum += __shfl_xor(sum, o);
  __shared__ float reds[4];
  if ((t & 63) == 0) reds[wid] = sum;
  __syncthreads();
  sum = reds[0] + reds[1] + reds[2] + reds[3];
  float inv = 1.0f / sum;
#pragma unroll
  for (int j = 0; j < 4; ++j) {
    v[j].x *= inv;
    v[j].y *= inv;
    v[j].z *= inv;
    v[j].w *= inv;
    __builtin_nontemporal_store(v[j], (f32x4*)(p + j * 1024 + t * 4));
    u16x4 o16 = {f2bf(v[j].x), f2bf(v[j].y), f2bf(v[j].z), f2bf(v[j].w)};
    *(u16x4*)(pbp + j * 1024 + t * 4) = o16;
  }
}

extern "C" void kernel_launch(void* const* d_in, const int* in_sizes, int n_in,
                              void* d_out, int out_size, void* d_ws, size_t ws_size,
                              hipStream_t stream) {
  const float* x = (const float*)d_in[0];
  const float* mask = (const float*)d_in[1];
  const float* Wq = (const float*)d_in[2];
  const float* Wk = (const float*)d_in[3];
  const float* Wv = (const float*)d_in[4];
  float* out = (float*)d_out;                           // [B][C][E]
  float* weights = out + (long)NBATCH * C_LEN * E_DIM;  // [B][C][C]

  char* ws = (char*)d_ws;
  const bool big = ws_size >= (160ull << 20);
  float* cosT = (float*)(ws);
  float* sinT = (float*)(ws + (8l << 20));
  unsigned short* x_bf = (unsigned short*)(ws + (16l << 20));
  unsigned short* W_bf = (unsigned short*)(ws + (48l << 20));  // [3072][1024] = Q|K|V
  unsigned short* Q_bf = (unsigned short*)(ws + (54l << 20));
  unsigned short* K_bf = (unsigned short*)(ws + (86l << 20));
  unsigned short* Vt = (unsigned short*)(ws + (big ? (128l << 20) : (118l << 20)));
  unsigned short* P_bf = (unsigned short*)(ws);

  dim3 blk(256);
  dim3 blk512(512);

  rope_table<<<dim3((C_LEN * (E_DIM / 2)) / 256), blk, 0, stream>>>(cosT, sinT);
  cvt_all<<<dim3(19456), blk, 0, stream>>>(x, Wq, Wk, Wv, x_bf, W_bf);

  // fused QKV projection: 64 rt x 12 ct = 768 blocks
  gemm8<0><<<dim3(768), blk512, 0, stream>>>(
      x_bf, W_bf, 0, 0, 0, 64, 12, E_DIM, 3 * E_DIM,
      Q_bf, K_bf, Vt, nullptr, cosT, sinT, nullptr);

  // scores = QK^T/32 + mask -> 16 rt x 16 ct x 4 bz = 1024 blocks
  gemm8<2><<<dim3(1024), blk512, 0, stream>>>(
      Q_bf, K_bf, (long)C_LEN * E_DIM, (long)C_LEN * E_DIM, (long)C_LEN * C_LEN,
      16, 16, E_DIM, C_LEN, nullptr, nullptr, nullptr, weights, nullptr, nullptr, mask);

  if (big) {
    softmax_rows<<<dim3(NBATCH * C_LEN), blk, 0, stream>>>(weights, P_bf);
    // out = P @ V: 16 rt x 4 ct x 4 bz = 256 blocks
    gemm8<3><<<dim3(256), blk512, 0, stream>>>(
        P_bf, Vt, (long)C_LEN * C_LEN, (long)E_DIM * C_LEN, (long)C_LEN * E_DIM,
        16, 4, C_LEN, E_DIM, nullptr, nullptr, nullptr, out, nullptr, nullptr, nullptr);
  } else {
    for (int h = 0; h < 2; ++h) {
      float* wgt = weights + (long)h * 2 * C_LEN * C_LEN;
      softmax_rows<<<dim3(2 * C_LEN), blk, 0, stream>>>(wgt, P_bf);
      gemm8<3><<<dim3(128), blk512, 0, stream>>>(
          P_bf, Vt + (long)h * 2 * E_DIM * C_LEN, (long)C_LEN * C_LEN, (long)E_DIM * C_LEN,
          (long)C_LEN * E_DIM, 16, 4, C_LEN, E_DIM,
          nullptr, nullptr, nullptr, out + (long)h * 2 * C_LEN * E_DIM,
          nullptr, nullptr, nullptr);
    }
  }
}